// Round 13
// baseline (209.193 us; speedup 1.0000x reference)
//
#include <hip/hip_runtime.h>
#include <math.h>

#define ROI 7
#define NC 256          // channels per modality
#define TC 512          // 2*NC concatenated
#define HH 128
#define WW 128
#define HW (HH * WW)    // 16384

// ---------------------------------------------------------------------------
__global__ void init_owner_k(int* __restrict__ owner, int n) {
    int i = blockIdx.x * blockDim.x + threadIdx.x;
    if (i < n) owner[i] = -1;
}

__global__ void mark_owner_k(const float* __restrict__ anchors,
                             int* __restrict__ owner, int B, int N) {
    int i = blockIdx.x * blockDim.x + threadIdx.x;
    int total = B * N * 49;
    if (i >= total) return;
    int p = i % 49;
    int bn = i / 49;
    int n = bn % N;
    int b = bn / N;
    float ax = anchors[(size_t)(b * N + n) * 3 + 0];
    float ay = anchors[(size_t)(b * N + n) * 3 + 1];
    int x0 = (int)truncf(ax - 3.5f); x0 = min(max(x0, 0), WW - ROI);
    int y0 = (int)truncf(ay - 3.5f); y0 = min(max(y0, 0), HH - ROI);
    int x = x0 + (p % 7);
    int y = y0 + (p / 7);
    atomicMax(&owner[((size_t)b << 14) + (y << 7) + x], n);
}

// ---------------------------------------------------------------------------
__device__ inline void axis_w(float X, int limit, float& w0, float& w1) {
    float x = fmaxf(X, 0.0f);
    int ix = (int)floorf(x);
    float l = (ix >= limit - 1) ? 0.0f : x - (float)min(ix, limit - 1);
    w0 = 1.0f - l;
    w1 = l;
}

// ---------------------------------------------------------------------------
// Merged kernel, 1024-thread blocks (R12 post-mortem: kernel time invariant
// to HBM traffic -> latency-bound, not BW-bound; so double waves/CU and
// halve every per-thread serial chain).
//  roi : 64 grid-lanes x 16 groups of 16 channels (2 load batches of 8+8).
//  fuse: 16 px-quads x 64 groups of 4 channels, shfl_xor pre-reduce (4 g/wave)
// __launch_bounds__(1024,8): VGPR<=64 -> 2 blocks/CU = 32 waves resident.
// ---------------------------------------------------------------------------
__global__ __launch_bounds__(1024, 8) void fused_k(
        const float* __restrict__ rgb, const float* __restrict__ tir,
        const float* __restrict__ a_rgb, const float* __restrict__ a_tir,
        const float* __restrict__ wg, const float* __restrict__ bg,
        const float* __restrict__ wa, const float* __restrict__ ba,
        const int* __restrict__ owner, float* __restrict__ out,
        int N, int nRoi, int nFuse) {
    __shared__ float w[2 * TC];
    __shared__ float part0[64][17];
    __shared__ float part1[64][17];
    __shared__ __align__(16) float att[64];

    int bid = blockIdx.x;
    int tid = threadIdx.x;

    bool isRoi;
    int idx;
    if (nFuse == 2 * nRoi) {             // interleaved mapping (1 roi : 2 fuse)
        int q3 = bid / 3, r3 = bid - 3 * q3;
        isRoi = (r3 == 0);
        idx = isRoi ? q3 : (bid - q3 - 1);
    } else {
        isRoi = (bid < nRoi);
        idx = isRoi ? bid : (bid - nRoi);
    }

    if (isRoi) {
        // ================= ROI align + fuse + owner-gated scatter =========
        int p  = tid & 63;               // grid lane (8x8 corner grid)
        int g  = tid >> 6;               // 0..15 -> 16 channels each
        int c0 = g << 4;
        int b = idx / N, n = idx % N;
        if (tid < 2 * TC) w[tid] = wa[tid];

        int lx = p & 7, ly = p >> 3;
        bool isPt = (lx < 7) && (ly < 7);

        float axr = a_rgb[(size_t)(b * N + n) * 3 + 0];
        float ayr = a_rgb[(size_t)(b * N + n) * 3 + 1];
        float axt = a_tir[(size_t)(b * N + n) * 3 + 0];
        float ayt = a_tir[(size_t)(b * N + n) * 3 + 1];

        int gx0r = max(0, (int)floorf(axr - 3.0f));
        int gy0r = max(0, (int)floorf(ayr - 3.0f));
        int gx0t = max(0, (int)floorf(axt - 3.0f));
        int gy0t = max(0, (int)floorf(ayt - 3.0f));
        int offr = (min(gy0r + ly, HH - 1) << 7) + min(gx0r + lx, WW - 1);
        int offt = (min(gy0t + ly, HH - 1) << 7) + min(gx0t + lx, WW - 1);

        float Xr = (axr - 3.5f) + ((float)lx + 0.5f);
        float Yr = (ayr - 3.5f) + ((float)ly + 0.5f);
        float Xt = (axt - 3.5f) + ((float)lx + 0.5f);
        float Yt = (ayt - 3.5f) + ((float)ly + 0.5f);

        float wxr0, wxr1, wyr0, wyr1, wxt0, wxt1, wyt0, wyt1;
        axis_w(Xr, WW, wxr0, wxr1);
        axis_w(Yr, HH, wyr0, wyr1);
        axis_w(Xt, WW, wxt0, wxt1);
        axis_w(Yt, HH, wyt0, wyt1);
        bool vldr = (Xr >= -1.0f) && (Xr <= (float)WW) && (Yr >= -1.0f) && (Yr <= (float)HH);
        bool vldt = (Xt >= -1.0f) && (Xt <= (float)WW) && (Yt >= -1.0f) && (Yt <= (float)HH);
        float sr = vldr ? 1.0f : 0.0f;
        float st = vldt ? 1.0f : 0.0f;

        int x0 = (int)truncf(axr - 3.5f); x0 = min(max(x0, 0), WW - ROI);
        int y0 = (int)truncf(ayr - 3.5f); y0 = min(max(y0, 0), HH - ROI);
        int x = x0 + lx, y = y0 + ly;
        bool act = isPt;
        if (act) act = (owner[((size_t)b << 14) + (y << 7) + x] == n);

        const float* rb = rgb + (((size_t)b * NC) << 14);
        const float* tb = tir + (((size_t)b * NC) << 14);

        __syncthreads();

        float vr[16], vt[16];
        float l0 = 0.f, l1 = 0.f;
        #pragma unroll
        for (int ii = 0; ii < 2; ++ii) {
            float gr[8], gt[8];
            #pragma unroll
            for (int j = 0; j < 8; ++j) {
                int c = c0 + (ii << 3) + j;
                gr[j] = rb[((size_t)c << 14) + offr];
                gt[j] = tb[((size_t)c << 14) + offt];
            }
            #pragma unroll
            for (int j = 0; j < 8; ++j) {
                int i = (ii << 3) + j;
                int c = c0 + i;
                float hr = wxr0 * gr[j] + wxr1 * __shfl_down(gr[j], 1, 64);
                float vvr = wyr0 * hr + wyr1 * __shfl_down(hr, 8, 64);
                vr[i] = sr * vvr;
                float ht = wxt0 * gt[j] + wxt1 * __shfl_down(gt[j], 1, 64);
                float vvt = wyt0 * ht + wyt1 * __shfl_down(ht, 8, 64);
                vt[i] = st * vvt;
                l0 = fmaf(w[c],          vr[i], fmaf(w[NC + c],     vt[i], l0));
                l1 = fmaf(w[2 * NC + c], vr[i], fmaf(w[3 * NC + c], vt[i], l1));
            }
        }
        part0[p][g] = l0;
        part1[p][g] = l1;
        __syncthreads();
        if (g == 0 && isPt) {
            float L0 = ba[0], L1 = ba[1];
            #pragma unroll
            for (int s = 0; s < 16; ++s) { L0 += part0[p][s]; L1 += part1[p][s]; }
            float m = fmaxf(L0, L1);
            float e0 = expf(L0 - m), e1 = expf(L1 - m);
            att[p] = e0 / (e0 + e1);
        }
        __syncthreads();
        if (!act) return;

        float a0 = att[p];
        float* po = out + (((size_t)b * NC) << 14) + (y << 7) + x;
        #pragma unroll
        for (int i = 0; i < 16; ++i) {
            int c = c0 + i;
            po[(size_t)c << 14] = fmaf(a0, vr[i] - vt[i], vt[i]);
        }
    } else {
        // ================= global per-pixel fusion (float4) ===============
        int q  = tid & 15;               // pixel quad (4 px)
        int g  = tid >> 4;               // 0..63 -> 4 channels each
        int c0 = g << 2;
        int b = idx >> 8;                // 256 fuse-blocks per image
        int pix0 = (idx & 255) << 6;
        int px0 = q << 2;
        if (tid < 2 * TC) w[tid] = wg[tid];

        int4 ow4 = *reinterpret_cast<const int4*>(
            owner + (((size_t)b << 14) + pix0 + px0));
        bool av0 = ow4.x < 0, av1 = ow4.y < 0, av2 = ow4.z < 0, av3 = ow4.w < 0;
        bool any = av0 | av1 | av2 | av3;

        const float* pr = rgb + (((size_t)b * NC) << 14) + pix0 + px0;
        const float* pt = tir + (((size_t)b * NC) << 14) + pix0 + px0;

        __syncthreads();

        float4 vr4[4], vt4[4];
        float l0a = 0.f, l0b = 0.f, l0c = 0.f, l0d = 0.f;
        float l1a = 0.f, l1b = 0.f, l1c = 0.f, l1d = 0.f;
        if (any) {
            #pragma unroll
            for (int j = 0; j < 4; ++j) {
                int c = c0 + j;
                vr4[j] = *reinterpret_cast<const float4*>(pr + ((size_t)c << 14));
                vt4[j] = *reinterpret_cast<const float4*>(pt + ((size_t)c << 14));
            }
            #pragma unroll
            for (int j = 0; j < 4; ++j) {
                int c = c0 + j;
                float wr0 = w[c], wt0 = w[NC + c];
                float wr1 = w[2 * NC + c], wt1 = w[3 * NC + c];
                l0a = fmaf(wr0, vr4[j].x, fmaf(wt0, vt4[j].x, l0a));
                l0b = fmaf(wr0, vr4[j].y, fmaf(wt0, vt4[j].y, l0b));
                l0c = fmaf(wr0, vr4[j].z, fmaf(wt0, vt4[j].z, l0c));
                l0d = fmaf(wr0, vr4[j].w, fmaf(wt0, vt4[j].w, l0d));
                l1a = fmaf(wr1, vr4[j].x, fmaf(wt1, vt4[j].x, l1a));
                l1b = fmaf(wr1, vr4[j].y, fmaf(wt1, vt4[j].y, l1b));
                l1c = fmaf(wr1, vr4[j].z, fmaf(wt1, vt4[j].z, l1c));
                l1d = fmaf(wr1, vr4[j].w, fmaf(wt1, vt4[j].w, l1d));
            }
        }
        // intra-wave reduce over the wave's 4 g-values (lanes l, l^16, l^32, l^48
        // share the same quad q = lane&15) -- executed by ALL lanes (uniform).
        l0a += __shfl_xor(l0a, 16, 64); l0a += __shfl_xor(l0a, 32, 64);
        l0b += __shfl_xor(l0b, 16, 64); l0b += __shfl_xor(l0b, 32, 64);
        l0c += __shfl_xor(l0c, 16, 64); l0c += __shfl_xor(l0c, 32, 64);
        l0d += __shfl_xor(l0d, 16, 64); l0d += __shfl_xor(l0d, 32, 64);
        l1a += __shfl_xor(l1a, 16, 64); l1a += __shfl_xor(l1a, 32, 64);
        l1b += __shfl_xor(l1b, 16, 64); l1b += __shfl_xor(l1b, 32, 64);
        l1c += __shfl_xor(l1c, 16, 64); l1c += __shfl_xor(l1c, 32, 64);
        l1d += __shfl_xor(l1d, 16, 64); l1d += __shfl_xor(l1d, 32, 64);
        if ((tid & 63) < 16) {
            int wv = tid >> 6;           // wave id 0..15
            part0[px0 + 0][wv] = l0a; part1[px0 + 0][wv] = l1a;
            part0[px0 + 1][wv] = l0b; part1[px0 + 1][wv] = l1b;
            part0[px0 + 2][wv] = l0c; part1[px0 + 2][wv] = l1c;
            part0[px0 + 3][wv] = l0d; part1[px0 + 3][wv] = l1d;
        }
        __syncthreads();
        if (tid < 64) {
            float L0 = bg[0], L1 = bg[1];
            #pragma unroll
            for (int s = 0; s < 16; ++s) { L0 += part0[tid][s]; L1 += part1[tid][s]; }
            float m = fmaxf(L0, L1);
            float e0 = expf(L0 - m), e1 = expf(L1 - m);
            att[tid] = e0 / (e0 + e1);
        }
        __syncthreads();
        if (!any) return;

        float4 a4 = *reinterpret_cast<float4*>(&att[px0]);
        bool all4 = av0 & av1 & av2 & av3;
        float* po = out + (((size_t)b * NC) << 14) + pix0 + px0;
        #pragma unroll
        for (int j = 0; j < 4; ++j) {
            int c = c0 + j;
            float4 o;
            o.x = fmaf(a4.x, vr4[j].x - vt4[j].x, vt4[j].x);
            o.y = fmaf(a4.y, vr4[j].y - vt4[j].y, vt4[j].y);
            o.z = fmaf(a4.z, vr4[j].z - vt4[j].z, vt4[j].z);
            o.w = fmaf(a4.w, vr4[j].w - vt4[j].w, vt4[j].w);
            float* dst = po + ((size_t)c << 14);
            if (all4) {
                *reinterpret_cast<float4*>(dst) = o;
            } else {
                if (av0) dst[0] = o.x;
                if (av1) dst[1] = o.y;
                if (av2) dst[2] = o.z;
                if (av3) dst[3] = o.w;
            }
        }
    }
}

// ---------------------------------------------------------------------------
extern "C" void kernel_launch(void* const* d_in, const int* in_sizes, int n_in,
                              void* d_out, int out_size, void* d_ws, size_t ws_size,
                              hipStream_t stream) {
    const float* frgb = (const float*)d_in[0];
    const float* ftir = (const float*)d_in[1];
    const float* argb = (const float*)d_in[2];
    const float* atir = (const float*)d_in[3];
    const float* wg   = (const float*)d_in[4];
    const float* bgp  = (const float*)d_in[5];
    const float* wa   = (const float*)d_in[6];
    const float* bap  = (const float*)d_in[7];
    float* out = (float*)d_out;

    int B = in_sizes[0] / (NC * HW);       // 8
    int N = in_sizes[2] / (B * 3);         // 128
    int npix = B * HW;                     // 131072
    int nRoi = B * N;                      // 1024
    int nFuse = npix / 64;                 // 2048

    int* owner = (int*)d_ws;               // B*H*W ints = 512 KB

    init_owner_k<<<(npix + 255) / 256, 256, 0, stream>>>(owner, npix);
    mark_owner_k<<<(B * N * 49 + 255) / 256, 256, 0, stream>>>(argb, owner, B, N);
    fused_k<<<nRoi + nFuse, 1024, 0, stream>>>(frgb, ftir, argb, atir,
                                               wg, bgp, wa, bap,
                                               owner, out, N, nRoi, nFuse);
}

// Round 14
// 207.133 us; speedup vs baseline: 1.0099x; 1.0099x over previous
//
#include <hip/hip_runtime.h>
#include <math.h>

#define ROI 7
#define NC 256          // channels per modality
#define TC 512          // 2*NC concatenated
#define HH 128
#define WW 128
#define HW (HH * WW)    // 16384

// ---------------------------------------------------------------------------
// Owner map: owner[b][y][x] = max anchor index n whose scattered 7x7 patch
// covers (y,x), else -1. Sequential overwrite == "last (max) anchor wins".
// ---------------------------------------------------------------------------
__global__ void init_owner_k(int* __restrict__ owner, int n) {
    int i = blockIdx.x * blockDim.x + threadIdx.x;
    if (i < n) owner[i] = -1;
}

__global__ void mark_owner_k(const float* __restrict__ anchors,
                             int* __restrict__ owner, int B, int N) {
    int i = blockIdx.x * blockDim.x + threadIdx.x;
    int total = B * N * 49;
    if (i >= total) return;
    int p = i % 49;
    int bn = i / 49;
    int n = bn % N;
    int b = bn / N;
    float ax = anchors[(size_t)(b * N + n) * 3 + 0];
    float ay = anchors[(size_t)(b * N + n) * 3 + 1];
    int x0 = (int)truncf(ax - 3.5f); x0 = min(max(x0, 0), WW - ROI);
    int y0 = (int)truncf(ay - 3.5f); y0 = min(max(y0, 0), HH - ROI);
    int x = x0 + (p % 7);
    int y = y0 + (p / 7);
    atomicMax(&owner[((size_t)b << 14) + (y << 7) + x], n);
}

// ---------------------------------------------------------------------------
__device__ inline void axis_w(float X, int limit, float& w0, float& w1) {
    float x = fmaxf(X, 0.0f);
    int ix = (int)floorf(x);
    float l = (ix >= limit - 1) ? 0.0f : x - (float)min(ix, limit - 1);
    w0 = 1.0f - l;
    w1 = l;
}

// ---------------------------------------------------------------------------
// K1: global fusion + roi-logit FIELDS. Pure streaming: reads every pixel's
// 512 channels (coalesced dwords), accumulates 6 dot products (2 global-fuse
// logits with wg; 4 roi-attention field components with wa), writes the
// global blend for ALL pixels (full lines, no owner mask -- roi_k overwrites
// owned pixels afterwards) + a float4 field per pixel (2 MB).
// Field swap-of-sums: logit_roi(p) = bilinear_p( F(corner) ), exact in reals.
// ---------------------------------------------------------------------------
__global__ __launch_bounds__(512) void fuse_fields_k(
        const float* __restrict__ rgb, const float* __restrict__ tir,
        const float* __restrict__ wg, const float* __restrict__ bg,
        const float* __restrict__ wa,
        float* __restrict__ out, float4* __restrict__ lf) {
    __shared__ float swg[2 * TC];
    __shared__ float swa[2 * TC];
    __shared__ float part[6][64][9];
    __shared__ float att[64];

    int tid = threadIdx.x;
    int b = blockIdx.x >> 8;             // 256 blocks per image
    int pix0 = (blockIdx.x & 255) << 6;
    int px = tid & 63, g = tid >> 6, c0 = g << 5;

    for (int i = tid; i < 2 * TC; i += 512) { swg[i] = wg[i]; swa[i] = wa[i]; }

    const float* pr = rgb + (((size_t)b * NC) << 14) + pix0 + px;
    const float* pt = tir + (((size_t)b * NC) << 14) + pix0 + px;

    __syncthreads();

    float vr[32], vt[32];
    float lg0 = 0.f, lg1 = 0.f, f0r = 0.f, f1r = 0.f, f0t = 0.f, f1t = 0.f;
    #pragma unroll
    for (int i = 0; i < 32; ++i) {
        int c = c0 + i;
        vr[i] = pr[(size_t)c << 14];
        vt[i] = pt[(size_t)c << 14];
        lg0 = fmaf(swg[c],          vr[i], fmaf(swg[NC + c],     vt[i], lg0));
        lg1 = fmaf(swg[2 * NC + c], vr[i], fmaf(swg[3 * NC + c], vt[i], lg1));
        f0r = fmaf(swa[c],          vr[i], f0r);
        f1r = fmaf(swa[2 * NC + c], vr[i], f1r);
        f0t = fmaf(swa[NC + c],     vt[i], f0t);
        f1t = fmaf(swa[3 * NC + c], vt[i], f1t);
    }
    part[0][px][g] = lg0; part[1][px][g] = lg1;
    part[2][px][g] = f0r; part[3][px][g] = f1r;
    part[4][px][g] = f0t; part[5][px][g] = f1t;
    __syncthreads();

    if (tid < 64) {
        float s[6];
        #pragma unroll
        for (int k = 0; k < 6; ++k) {
            float acc = 0.f;
            #pragma unroll
            for (int q = 0; q < 8; ++q) acc += part[k][tid][q];
            s[k] = acc;
        }
        float L0 = bg[0] + s[0], L1 = bg[1] + s[1];
        float m = fmaxf(L0, L1);
        float e0 = expf(L0 - m), e1 = expf(L1 - m);
        att[tid] = e0 / (e0 + e1);
        lf[(size_t)b * HW + pix0 + tid] = make_float4(s[2], s[3], s[4], s[5]);
    }
    __syncthreads();

    float a0 = att[px];
    float* po = out + (((size_t)b * NC) << 14) + pix0 + px;
    #pragma unroll
    for (int i = 0; i < 32; ++i) {
        int c = c0 + i;
        po[(size_t)c << 14] = fmaf(a0, vr[i] - vt[i], vt[i]);
    }
}

// ---------------------------------------------------------------------------
// K2: roi value pass. NO barriers, NO LDS, NO channel reduction: the
// attention a0 per point comes from the bilinear of the precomputed fields
// (lane-local softmax). Then a free-flowing loop: gather channel -> 4 shfl
// bilinear -> blend -> predicated store. Iterations fully independent ->
// deep vmem pipelining, waves retire independently.
// ---------------------------------------------------------------------------
__global__ __launch_bounds__(512) void roi_k(
        const float* __restrict__ rgb, const float* __restrict__ tir,
        const float* __restrict__ a_rgb, const float* __restrict__ a_tir,
        const float* __restrict__ ba, const int* __restrict__ owner,
        const float4* __restrict__ lf, float* __restrict__ out, int N) {
    int tid = threadIdx.x;
    int b = blockIdx.x / N, n = blockIdx.x % N;
    int p = tid & 63, wid = tid >> 6, c0 = wid << 5;
    int lx = p & 7, ly = p >> 3;

    float axr = a_rgb[(size_t)(b * N + n) * 3 + 0];
    float ayr = a_rgb[(size_t)(b * N + n) * 3 + 1];
    float axt = a_tir[(size_t)(b * N + n) * 3 + 0];
    float ayt = a_tir[(size_t)(b * N + n) * 3 + 1];

    int gx0r = max(0, (int)floorf(axr - 3.0f));
    int gy0r = max(0, (int)floorf(ayr - 3.0f));
    int gx0t = max(0, (int)floorf(axt - 3.0f));
    int gy0t = max(0, (int)floorf(ayt - 3.0f));
    int offr = (min(gy0r + ly, HH - 1) << 7) + min(gx0r + lx, WW - 1);
    int offt = (min(gy0t + ly, HH - 1) << 7) + min(gx0t + lx, WW - 1);

    float Xr = (axr - 3.5f) + ((float)lx + 0.5f);
    float Yr = (ayr - 3.5f) + ((float)ly + 0.5f);
    float Xt = (axt - 3.5f) + ((float)lx + 0.5f);
    float Yt = (ayt - 3.5f) + ((float)ly + 0.5f);

    float wxr0, wxr1, wyr0, wyr1, wxt0, wxt1, wyt0, wyt1;
    axis_w(Xr, WW, wxr0, wxr1);
    axis_w(Yr, HH, wyr0, wyr1);
    axis_w(Xt, WW, wxt0, wxt1);
    axis_w(Yt, HH, wyt0, wyt1);
    bool vldr = (Xr >= -1.0f) && (Xr <= (float)WW) && (Yr >= -1.0f) && (Yr <= (float)HH);
    bool vldt = (Xt >= -1.0f) && (Xt <= (float)WW) && (Yt >= -1.0f) && (Yt <= (float)HH);
    float sr = vldr ? 1.0f : 0.0f;
    float st = vldt ? 1.0f : 0.0f;

    int x0 = (int)truncf(axr - 3.5f); x0 = min(max(x0, 0), WW - ROI);
    int y0 = (int)truncf(ayr - 3.5f); y0 = min(max(y0, 0), HH - ROI);
    int x = x0 + lx, y = y0 + ly;
    bool act = (lx < 7) && (ly < 7);
    if (act) act = (owner[((size_t)b << 14) + (y << 7) + x] == n);

    // ---- attention from fields (lane-local softmax)
    float4 Fr = lf[(size_t)b * HW + offr];
    float4 Ft = lf[(size_t)b * HW + offt];
    float h0 = wxr0 * Fr.x + wxr1 * __shfl_down(Fr.x, 1, 64);
    float G0r = wyr0 * h0 + wyr1 * __shfl_down(h0, 8, 64);
    float h1 = wxr0 * Fr.y + wxr1 * __shfl_down(Fr.y, 1, 64);
    float G1r = wyr0 * h1 + wyr1 * __shfl_down(h1, 8, 64);
    float h2 = wxt0 * Ft.z + wxt1 * __shfl_down(Ft.z, 1, 64);
    float G0t = wyt0 * h2 + wyt1 * __shfl_down(h2, 8, 64);
    float h3 = wxt0 * Ft.w + wxt1 * __shfl_down(Ft.w, 1, 64);
    float G1t = wyt0 * h3 + wyt1 * __shfl_down(h3, 8, 64);
    float L0 = ba[0] + sr * G0r + st * G0t;
    float L1 = ba[1] + sr * G1r + st * G1t;
    float m = fmaxf(L0, L1);
    float e0 = expf(L0 - m), e1 = expf(L1 - m);
    float a0 = e0 / (e0 + e1);

    // ---- value pass: independent iterations, predicated stores
    const float* rb = rgb + (((size_t)b * NC) << 14);
    const float* tb = tir + (((size_t)b * NC) << 14);
    float* po = out + (((size_t)b * NC) << 14) + (y << 7) + x;
    #pragma unroll
    for (int i = 0; i < 32; ++i) {
        int c = c0 + i;
        float gr = rb[((size_t)c << 14) + offr];
        float gt = tb[((size_t)c << 14) + offt];
        float hr = wxr0 * gr + wxr1 * __shfl_down(gr, 1, 64);
        float vvr = wyr0 * hr + wyr1 * __shfl_down(hr, 8, 64);
        float ht = wxt0 * gt + wxt1 * __shfl_down(gt, 1, 64);
        float vvt = wyt0 * ht + wyt1 * __shfl_down(ht, 8, 64);
        float vr = sr * vvr, vt = st * vvt;
        if (act) po[(size_t)c << 14] = fmaf(a0, vr - vt, vt);
    }
}

// ---------------------------------------------------------------------------
extern "C" void kernel_launch(void* const* d_in, const int* in_sizes, int n_in,
                              void* d_out, int out_size, void* d_ws, size_t ws_size,
                              hipStream_t stream) {
    const float* frgb = (const float*)d_in[0];
    const float* ftir = (const float*)d_in[1];
    const float* argb = (const float*)d_in[2];
    const float* atir = (const float*)d_in[3];
    const float* wg   = (const float*)d_in[4];
    const float* bgp  = (const float*)d_in[5];
    const float* wa   = (const float*)d_in[6];
    const float* bap  = (const float*)d_in[7];
    float* out = (float*)d_out;

    int B = in_sizes[0] / (NC * HW);       // 8
    int N = in_sizes[2] / (B * 3);         // 128
    int npix = B * HW;                     // 131072

    int* owner = (int*)d_ws;                                    // 512 KB
    float4* lf = (float4*)((char*)d_ws + (size_t)npix * 4);     // 2 MB fields

    init_owner_k<<<(npix + 255) / 256, 256, 0, stream>>>(owner, npix);
    mark_owner_k<<<(B * N * 49 + 255) / 256, 256, 0, stream>>>(argb, owner, B, N);
    fuse_fields_k<<<npix / 64, 512, 0, stream>>>(frgb, ftir, wg, bgp, wa, out, lf);
    roi_k<<<B * N, 512, 0, stream>>>(frgb, ftir, argb, atir, bap,
                                     owner, lf, out, N);
}

// Round 15
// 205.748 us; speedup vs baseline: 1.0167x; 1.0067x over previous
//
#include <hip/hip_runtime.h>
#include <math.h>

#define ROI 7
#define NC 256          // channels per modality
#define TC 512          // 2*NC concatenated
#define HH 128
#define WW 128
#define HW (HH * WW)    // 16384

// ---------------------------------------------------------------------------
__global__ void init_owner_k(int* __restrict__ owner, int n) {
    int i = blockIdx.x * blockDim.x + threadIdx.x;
    if (i < n) owner[i] = -1;
}

__global__ void mark_owner_k(const float* __restrict__ anchors,
                             int* __restrict__ owner, int B, int N) {
    int i = blockIdx.x * blockDim.x + threadIdx.x;
    int total = B * N * 49;
    if (i >= total) return;
    int p = i % 49;
    int bn = i / 49;
    int n = bn % N;
    int b = bn / N;
    float ax = anchors[(size_t)(b * N + n) * 3 + 0];
    float ay = anchors[(size_t)(b * N + n) * 3 + 1];
    int x0 = (int)truncf(ax - 3.5f); x0 = min(max(x0, 0), WW - ROI);
    int y0 = (int)truncf(ay - 3.5f); y0 = min(max(y0, 0), HH - ROI);
    int x = x0 + (p % 7);
    int y = y0 + (p / 7);
    atomicMax(&owner[((size_t)b << 14) + (y << 7) + x], n);
}

// ---------------------------------------------------------------------------
__device__ inline void axis_w(float X, int limit, float& w0, float& w1) {
    float x = fmaxf(X, 0.0f);
    int ix = (int)floorf(x);
    float l = (ix >= limit - 1) ? 0.0f : x - (float)min(ix, limit - 1);
    w0 = 1.0f - l;
    w1 = l;
}

// ---------------------------------------------------------------------------
// K1: global fusion + roi-logit fields. NONTEMPORAL out-stores: the 134 MB
// output stream must not evict the 268 MB of feature reads from L3 --
// roi_k re-reads those features as scattered lines (R14: 285 MB HBM random
// -> 125 us; L3-resident they're fast).
// ---------------------------------------------------------------------------
__global__ __launch_bounds__(512) void fuse_fields_k(
        const float* __restrict__ rgb, const float* __restrict__ tir,
        const float* __restrict__ wg, const float* __restrict__ bg,
        const float* __restrict__ wa,
        float* __restrict__ out, float4* __restrict__ lf) {
    __shared__ float swg[2 * TC];
    __shared__ float swa[2 * TC];
    __shared__ float part[6][64][9];
    __shared__ float att[64];

    int tid = threadIdx.x;
    int b = blockIdx.x >> 8;             // 256 blocks per image
    int pix0 = (blockIdx.x & 255) << 6;
    int px = tid & 63, g = tid >> 6, c0 = g << 5;

    for (int i = tid; i < 2 * TC; i += 512) { swg[i] = wg[i]; swa[i] = wa[i]; }

    const float* pr = rgb + (((size_t)b * NC) << 14) + pix0 + px;
    const float* pt = tir + (((size_t)b * NC) << 14) + pix0 + px;

    __syncthreads();

    float vr[32], vt[32];
    float lg0 = 0.f, lg1 = 0.f, f0r = 0.f, f1r = 0.f, f0t = 0.f, f1t = 0.f;
    #pragma unroll
    for (int i = 0; i < 32; ++i) {
        int c = c0 + i;
        vr[i] = pr[(size_t)c << 14];
        vt[i] = pt[(size_t)c << 14];
        lg0 = fmaf(swg[c],          vr[i], fmaf(swg[NC + c],     vt[i], lg0));
        lg1 = fmaf(swg[2 * NC + c], vr[i], fmaf(swg[3 * NC + c], vt[i], lg1));
        f0r = fmaf(swa[c],          vr[i], f0r);
        f1r = fmaf(swa[2 * NC + c], vr[i], f1r);
        f0t = fmaf(swa[NC + c],     vt[i], f0t);
        f1t = fmaf(swa[3 * NC + c], vt[i], f1t);
    }
    part[0][px][g] = lg0; part[1][px][g] = lg1;
    part[2][px][g] = f0r; part[3][px][g] = f1r;
    part[4][px][g] = f0t; part[5][px][g] = f1t;
    __syncthreads();

    if (tid < 64) {
        float s[6];
        #pragma unroll
        for (int k = 0; k < 6; ++k) {
            float acc = 0.f;
            #pragma unroll
            for (int q = 0; q < 8; ++q) acc += part[k][tid][q];
            s[k] = acc;
        }
        float L0 = bg[0] + s[0], L1 = bg[1] + s[1];
        float m = fmaxf(L0, L1);
        float e0 = expf(L0 - m), e1 = expf(L1 - m);
        att[tid] = e0 / (e0 + e1);
        lf[(size_t)b * HW + pix0 + tid] = make_float4(s[2], s[3], s[4], s[5]);
    }
    __syncthreads();

    float a0 = att[px];
    float* po = out + (((size_t)b * NC) << 14) + pix0 + px;
    #pragma unroll
    for (int i = 0; i < 32; ++i) {
        int c = c0 + i;
        __builtin_nontemporal_store(fmaf(a0, vr[i] - vt[i], vt[i]),
                                    po + ((size_t)c << 14));
    }
}

// ---------------------------------------------------------------------------
// K2: roi value pass -- barrier-free, LDS-free (fields give the softmax).
// Reverse image order (freshest-in-L3 first) + batched loads (16 in flight
// before the shuffle chains; R14's VGPR=20 showed no batching -> low MLP).
// ---------------------------------------------------------------------------
__global__ __launch_bounds__(512) void roi_k(
        const float* __restrict__ rgb, const float* __restrict__ tir,
        const float* __restrict__ a_rgb, const float* __restrict__ a_tir,
        const float* __restrict__ ba, const int* __restrict__ owner,
        const float4* __restrict__ lf, float* __restrict__ out, int N, int B) {
    int tid = threadIdx.x;
    int b = (B - 1) - blockIdx.x / N;    // reverse: L3-warm images first
    int n = blockIdx.x % N;
    int p = tid & 63, wid = tid >> 6, c0 = wid << 5;
    int lx = p & 7, ly = p >> 3;

    float axr = a_rgb[(size_t)(b * N + n) * 3 + 0];
    float ayr = a_rgb[(size_t)(b * N + n) * 3 + 1];
    float axt = a_tir[(size_t)(b * N + n) * 3 + 0];
    float ayt = a_tir[(size_t)(b * N + n) * 3 + 1];

    int gx0r = max(0, (int)floorf(axr - 3.0f));
    int gy0r = max(0, (int)floorf(ayr - 3.0f));
    int gx0t = max(0, (int)floorf(axt - 3.0f));
    int gy0t = max(0, (int)floorf(ayt - 3.0f));
    int offr = (min(gy0r + ly, HH - 1) << 7) + min(gx0r + lx, WW - 1);
    int offt = (min(gy0t + ly, HH - 1) << 7) + min(gx0t + lx, WW - 1);

    float Xr = (axr - 3.5f) + ((float)lx + 0.5f);
    float Yr = (ayr - 3.5f) + ((float)ly + 0.5f);
    float Xt = (axt - 3.5f) + ((float)lx + 0.5f);
    float Yt = (ayt - 3.5f) + ((float)ly + 0.5f);

    float wxr0, wxr1, wyr0, wyr1, wxt0, wxt1, wyt0, wyt1;
    axis_w(Xr, WW, wxr0, wxr1);
    axis_w(Yr, HH, wyr0, wyr1);
    axis_w(Xt, WW, wxt0, wxt1);
    axis_w(Yt, HH, wyt0, wyt1);
    bool vldr = (Xr >= -1.0f) && (Xr <= (float)WW) && (Yr >= -1.0f) && (Yr <= (float)HH);
    bool vldt = (Xt >= -1.0f) && (Xt <= (float)WW) && (Yt >= -1.0f) && (Yt <= (float)HH);
    float sr = vldr ? 1.0f : 0.0f;
    float st = vldt ? 1.0f : 0.0f;

    int x0 = (int)truncf(axr - 3.5f); x0 = min(max(x0, 0), WW - ROI);
    int y0 = (int)truncf(ayr - 3.5f); y0 = min(max(y0, 0), HH - ROI);
    int x = x0 + lx, y = y0 + ly;
    bool act = (lx < 7) && (ly < 7);
    if (act) act = (owner[((size_t)b << 14) + (y << 7) + x] == n);

    // ---- attention from fields (lane-local softmax)
    float4 Fr = lf[(size_t)b * HW + offr];
    float4 Ft = lf[(size_t)b * HW + offt];
    float h0 = wxr0 * Fr.x + wxr1 * __shfl_down(Fr.x, 1, 64);
    float G0r = wyr0 * h0 + wyr1 * __shfl_down(h0, 8, 64);
    float h1 = wxr0 * Fr.y + wxr1 * __shfl_down(Fr.y, 1, 64);
    float G1r = wyr0 * h1 + wyr1 * __shfl_down(h1, 8, 64);
    float h2 = wxt0 * Ft.z + wxt1 * __shfl_down(Ft.z, 1, 64);
    float G0t = wyt0 * h2 + wyt1 * __shfl_down(h2, 8, 64);
    float h3 = wxt0 * Ft.w + wxt1 * __shfl_down(Ft.w, 1, 64);
    float G1t = wyt0 * h3 + wyt1 * __shfl_down(h3, 8, 64);
    float L0 = ba[0] + sr * G0r + st * G0t;
    float L1 = ba[1] + sr * G1r + st * G1t;
    float m = fmaxf(L0, L1);
    float e0 = expf(L0 - m), e1 = expf(L1 - m);
    float a0 = e0 / (e0 + e1);

    // ---- value pass: batches of 16 independent loads, then shuffles
    const float* rb = rgb + (((size_t)b * NC) << 14);
    const float* tb = tir + (((size_t)b * NC) << 14);
    float* po = out + (((size_t)b * NC) << 14) + (y << 7) + x;
    #pragma unroll
    for (int ii = 0; ii < 4; ++ii) {
        float gr[8], gt[8];
        #pragma unroll
        for (int j = 0; j < 8; ++j) {
            int c = c0 + (ii << 3) + j;
            gr[j] = rb[((size_t)c << 14) + offr];
            gt[j] = tb[((size_t)c << 14) + offt];
        }
        #pragma unroll
        for (int j = 0; j < 8; ++j) {
            int c = c0 + (ii << 3) + j;
            float hr = wxr0 * gr[j] + wxr1 * __shfl_down(gr[j], 1, 64);
            float vvr = wyr0 * hr + wyr1 * __shfl_down(hr, 8, 64);
            float ht = wxt0 * gt[j] + wxt1 * __shfl_down(gt[j], 1, 64);
            float vvt = wyt0 * ht + wyt1 * __shfl_down(ht, 8, 64);
            float vr = sr * vvr, vt = st * vvt;
            if (act) po[(size_t)c << 14] = fmaf(a0, vr - vt, vt);
        }
    }
}

// ---------------------------------------------------------------------------
extern "C" void kernel_launch(void* const* d_in, const int* in_sizes, int n_in,
                              void* d_out, int out_size, void* d_ws, size_t ws_size,
                              hipStream_t stream) {
    const float* frgb = (const float*)d_in[0];
    const float* ftir = (const float*)d_in[1];
    const float* argb = (const float*)d_in[2];
    const float* atir = (const float*)d_in[3];
    const float* wg   = (const float*)d_in[4];
    const float* bgp  = (const float*)d_in[5];
    const float* wa   = (const float*)d_in[6];
    const float* bap  = (const float*)d_in[7];
    float* out = (float*)d_out;

    int B = in_sizes[0] / (NC * HW);       // 8
    int N = in_sizes[2] / (B * 3);         // 128
    int npix = B * HW;                     // 131072

    int* owner = (int*)d_ws;                                    // 512 KB
    float4* lf = (float4*)((char*)d_ws + (size_t)npix * 4);     // 2 MB fields

    init_owner_k<<<(npix + 255) / 256, 256, 0, stream>>>(owner, npix);
    mark_owner_k<<<(B * N * 49 + 255) / 256, 256, 0, stream>>>(argb, owner, B, N);
    fuse_fields_k<<<npix / 64, 512, 0, stream>>>(frgb, ftir, wg, bgp, wa, out, lf);
    roi_k<<<B * N, 512, 0, stream>>>(frgb, ftir, argb, atir, bap,
                                     owner, lf, out, N, B);
}